// Round 2
// baseline (1151.269 us; speedup 1.0000x reference)
//
#include <hip/hip_runtime.h>
#include <hip/hip_bf16.h>

#define N_PTS 262144
#define STEP_LEN 0.0016914558667664818f

using f32x4 = __attribute__((ext_vector_type(4))) float;
using s8 = __attribute__((ext_vector_type(8))) short;

__device__ __forceinline__ float bf2f(short s) {
    union { unsigned int u; float f; } v;
    v.u = ((unsigned int)(unsigned short)s) << 16;
    return v.f;
}

// ---- workspace: bf16 weights pre-packed into MFMA B-fragment order ----
// layout per layer: [ntile][kstep][lane][8] bf16, where
//   n = ntile*16 + (lane&15), k = kstep*32 + ((lane>>4)<<3) + j
#define OFF_W1   0          // 256x64   (63 pad), KS=2  -> 16384
#define OFF_W1H  16384      // 3x 256x256, KS=8        -> 196608
#define OFF_W2   212992     // 256x320  (319 pad), KS=10 -> 81920
#define OFF_W2H  294912     // 3x 256x256, KS=8        -> 196608
#define OFF_WC1  491520     // 128x320  (283 pad), KS=10 -> 40960
#define WS_ELEMS 532480

__device__ __forceinline__ void pack_one(const float* __restrict__ W,
                                         int Kin, int KS,
                                         __hip_bfloat16* __restrict__ dst, int e) {
    int j = e & 7;
    int lane = (e >> 3) & 63;
    int rest = e >> 9;
    int ks = rest % KS;
    int ntile = rest / KS;
    int n = ntile * 16 + (lane & 15);
    int k = ks * 32 + ((lane >> 4) << 3) + j;
    float v = (k < Kin) ? W[n * Kin + k] : 0.f;
    dst[e] = __float2bfloat16(v);
}

__global__ void prep_weights(const float* __restrict__ w1_in,
                             const float* __restrict__ w1_h,
                             const float* __restrict__ w2_in,
                             const float* __restrict__ w2_h,
                             const float* __restrict__ w_c1,
                             __hip_bfloat16* __restrict__ ws) {
    int i = blockIdx.x * blockDim.x + threadIdx.x;
    if (i >= WS_ELEMS) return;
    if (i < OFF_W1H) {
        pack_one(w1_in, 63, 2, ws + OFF_W1, i - OFF_W1);
    } else if (i < OFF_W2) {
        int e = i - OFF_W1H;
        int sub = e / 65536, ee = e % 65536;
        pack_one(w1_h + sub * 65536, 256, 8, ws + OFF_W1H + sub * 65536, ee);
    } else if (i < OFF_W2H) {
        pack_one(w2_in, 319, 10, ws + OFF_W2, i - OFF_W2);
    } else if (i < OFF_WC1) {
        int e = i - OFF_W2H;
        int sub = e / 65536, ee = e % 65536;
        pack_one(w2_h + sub * 65536, 256, 8, ws + OFF_W2H + sub * 65536, ee);
    } else {
        pack_one(w_c1, 283, 10, ws + OFF_WC1, i - OFF_WC1);
    }
}

// out[128 x 16*NT] = relu(in[128 x 32*KS] * W^T + bias), written IN PLACE into
// the same LDS buffer (cols 0..16*NT*8waves) after an internal barrier.
// LDS rows: byte stride 640, swizzle: byte ^= (row&7)<<4.
// Each wave: all 8 m-tiles (128 rows) x NT n-tiles at n0.
template<int NT, int KS>
__device__ __forceinline__ void gemm_layer(
    char* __restrict__ lds, const int inOff,
    const __hip_bfloat16* __restrict__ Wp,
    const float* __restrict__ bias,
    const int n0, const int lane) {

    const int rlo = lane & 15;
    const int asw = (rlo & 7) << 4;

    f32x4 acc[8][NT];
#pragma unroll
    for (int mt = 0; mt < 8; ++mt)
#pragma unroll
        for (int nt = 0; nt < NT; ++nt)
            acc[mt][nt] = f32x4{0.f, 0.f, 0.f, 0.f};

    const s8* bptr[NT];
#pragma unroll
    for (int nt = 0; nt < NT; ++nt)
        bptr[nt] = (const s8*)Wp + ((n0 >> 4) + nt) * (KS * 64) + lane;

    int abase[8];
#pragma unroll
    for (int mt = 0; mt < 8; ++mt) {
        int row = mt * 16 + rlo;
        abase[mt] = row * 640 + inOff + ((lane >> 4) << 4);
    }

    s8 bA[NT], bB[NT];
#pragma unroll
    for (int nt = 0; nt < NT; ++nt) bA[nt] = bptr[nt][0];

    auto kstep = [&](int ks, s8* bf) {
        s8 a0, a1, a2, a3;
        int ko = ks * 64;
        a0 = *(const s8*)(lds + ((abase[0] + ko) ^ asw));
        a1 = *(const s8*)(lds + ((abase[1] + ko) ^ asw));
        a2 = *(const s8*)(lds + ((abase[2] + ko) ^ asw));
        a3 = *(const s8*)(lds + ((abase[3] + ko) ^ asw));
#pragma unroll
        for (int nt = 0; nt < NT; ++nt) {
            acc[0][nt] = __builtin_amdgcn_mfma_f32_16x16x32_bf16(a0, bf[nt], acc[0][nt], 0, 0, 0);
            acc[1][nt] = __builtin_amdgcn_mfma_f32_16x16x32_bf16(a1, bf[nt], acc[1][nt], 0, 0, 0);
            acc[2][nt] = __builtin_amdgcn_mfma_f32_16x16x32_bf16(a2, bf[nt], acc[2][nt], 0, 0, 0);
            acc[3][nt] = __builtin_amdgcn_mfma_f32_16x16x32_bf16(a3, bf[nt], acc[3][nt], 0, 0, 0);
        }
        a0 = *(const s8*)(lds + ((abase[4] + ko) ^ asw));
        a1 = *(const s8*)(lds + ((abase[5] + ko) ^ asw));
        a2 = *(const s8*)(lds + ((abase[6] + ko) ^ asw));
        a3 = *(const s8*)(lds + ((abase[7] + ko) ^ asw));
#pragma unroll
        for (int nt = 0; nt < NT; ++nt) {
            acc[4][nt] = __builtin_amdgcn_mfma_f32_16x16x32_bf16(a0, bf[nt], acc[4][nt], 0, 0, 0);
            acc[5][nt] = __builtin_amdgcn_mfma_f32_16x16x32_bf16(a1, bf[nt], acc[5][nt], 0, 0, 0);
            acc[6][nt] = __builtin_amdgcn_mfma_f32_16x16x32_bf16(a2, bf[nt], acc[6][nt], 0, 0, 0);
            acc[7][nt] = __builtin_amdgcn_mfma_f32_16x16x32_bf16(a3, bf[nt], acc[7][nt], 0, 0, 0);
        }
    };

    for (int ks = 0; ks < KS; ks += 2) {
#pragma unroll
        for (int nt = 0; nt < NT; ++nt) bB[nt] = bptr[nt][(ks + 1) * 64];
        kstep(ks, bA);
        if (ks + 2 < KS) {
#pragma unroll
            for (int nt = 0; nt < NT; ++nt) bA[nt] = bptr[nt][(ks + 2) * 64];
        }
        kstep(ks + 1, bB);
    }

    __syncthreads();  // all waves done reading input -> in-place write safe

    const int rhi = (lane >> 4) << 2;
#pragma unroll
    for (int nt = 0; nt < NT; ++nt) {
        int n = n0 + nt * 16 + rlo;
        float bv = bias[n];
#pragma unroll
        for (int mt = 0; mt < 8; ++mt) {
            f32x4 v = acc[mt][nt];
#pragma unroll
            for (int r = 0; r < 4; ++r) {
                int row = mt * 16 + rhi + r;
                float x = fmaxf(v[r] + bv, 0.f);
                int byt = row * 640 + n * 2;
                *(__hip_bfloat16*)(lds + (byt ^ ((row & 7) << 4))) =
                    __float2bfloat16(x);
            }
        }
    }
}

__global__ __launch_bounds__(512, 4) void nerf_fused(
    const float* __restrict__ pos, const float* __restrict__ dir,
    const __hip_bfloat16* __restrict__ ws,
    const float* __restrict__ b1_in, const float* __restrict__ b1_h,
    const float* __restrict__ b2_in, const float* __restrict__ b2_h,
    const float* __restrict__ w_sigma, const float* __restrict__ b_sigma,
    const float* __restrict__ b_c1,
    const float* __restrict__ w_c2, const float* __restrict__ b_c2,
    float* __restrict__ out) {

    // single LDS buffer [128][320] bf16 = 80 KB -> 2 blocks/CU
    __shared__ __align__(16) __hip_bfloat16 sCat[128 * 320];
    char* L = (char*)sCat;

    const int t = threadIdx.x;
    const int lane = t & 63;
    const int wid = t >> 6;
    const int row0 = blockIdx.x * 128;

    // ---- positional encoding -> cols 256..319 (63 + zero pad)
    {
        int r = t >> 2, p = t & 3;
        int g = row0 + r;
        float x0 = pos[g * 3 + 0], x1 = pos[g * 3 + 1], x2 = pos[g * 3 + 2];
        for (int e = p; e < 64; e += 4) {
            float v;
            if (e < 3) {
                v = (e == 0) ? x0 : ((e == 1) ? x1 : x2);
            } else if (e < 33) {
                int j = e - 3; int c = j / 10, f = j % 10;
                float xc = (c == 0) ? x0 : ((c == 1) ? x1 : x2);
                v = sinf(xc * (float)(1 << f));
            } else if (e < 63) {
                int j = e - 33; int c = j / 10, f = j % 10;
                float xc = (c == 0) ? x0 : ((c == 1) ? x1 : x2);
                v = cosf(xc * (float)(1 << f));
            } else {
                v = 0.f;
            }
            int byt = r * 640 + (256 + e) * 2;
            *(__hip_bfloat16*)(L + (byt ^ ((r & 7) << 4))) = __float2bfloat16(v);
        }
    }
    __syncthreads();

    // ---- base_mlp_1: pe(64) -> 256, then 3x 256 -> 256
    gemm_layer<2, 2>(L, 512, ws + OFF_W1, b1_in, wid * 32, lane);
    __syncthreads();
    gemm_layer<2, 8>(L, 0, ws + OFF_W1H + 0 * 65536, b1_h + 0 * 256, wid * 32, lane);
    __syncthreads();
    gemm_layer<2, 8>(L, 0, ws + OFF_W1H + 1 * 65536, b1_h + 1 * 256, wid * 32, lane);
    __syncthreads();
    gemm_layer<2, 8>(L, 0, ws + OFF_W1H + 2 * 65536, b1_h + 2 * 256, wid * 32, lane);
    __syncthreads();
    // L = [h(256) | pe(63) | 0]

    // ---- base_mlp_2: 320 -> 256, then 3x 256 -> 256
    gemm_layer<2, 10>(L, 0, ws + OFF_W2, b2_in, wid * 32, lane);
    __syncthreads();
    gemm_layer<2, 8>(L, 0, ws + OFF_W2H + 0 * 65536, b2_h + 0 * 256, wid * 32, lane);
    __syncthreads();
    gemm_layer<2, 8>(L, 0, ws + OFF_W2H + 1 * 65536, b2_h + 1 * 256, wid * 32, lane);
    __syncthreads();
    gemm_layer<2, 8>(L, 0, ws + OFF_W2H + 2 * 65536, b2_h + 2 * 256, wid * 32, lane);
    __syncthreads();
    // g in cols 0..255

    // ---- sigma head: alpha out + sigma feature (bf16 into col 282)
    {
        int r = t >> 2, p = t & 3;
        float acc = 0.f;
        int kb = p * 64;
        for (int kk = 0; kk < 8; ++kk) {
            int k = kb + kk * 8;
            int byt = r * 640 + k * 2;
            s8 v = *(const s8*)(L + (byt ^ ((r & 7) << 4)));
#pragma unroll
            for (int j = 0; j < 8; ++j) acc += bf2f(v[j]) * w_sigma[k + j];
        }
        acc += __shfl_xor(acc, 1);
        acc += __shfl_xor(acc, 2);
        float sr = acc + b_sigma[0];
        if (p == 0) {
            out[3 * N_PTS + row0 + r] = 1.f - expf(-fmaxf(sr, 0.f) * STEP_LEN);
            int byt = r * 640 + (256 + 26) * 2;
            *(__hip_bfloat16*)(L + (byt ^ ((r & 7) << 4))) = __float2bfloat16(sr);
        }
    }
    __syncthreads();

    // ---- dir encoding -> cols 256..319 (26 + [282]=sigma + zero pad)
    {
        int r = t >> 2, p = t & 3;
        int g = row0 + r;
        float u0 = (dir[g * 3 + 0] + 1.f) * 0.5f;
        float u1 = (dir[g * 3 + 1] + 1.f) * 0.5f;
        float u2 = (dir[g * 3 + 2] + 1.f) * 0.5f;
        for (int e = p; e < 64; e += 4) {
            if (e == 26) continue;  // sigma feature already written
            float v;
            if (e < 13) {
                int c = e / 5, f = e % 5;
                float uc = (c == 0) ? u0 : ((c == 1) ? u1 : u2);
                v = sinf(uc * (float)(1 << f));
            } else if (e < 26) {
                int j = e - 13; int c = j / 5, f = j % 5;
                float uc = (c == 0) ? u0 : ((c == 1) ? u1 : u2);
                v = cosf(uc * (float)(1 << f));
            } else {
                v = 0.f;
            }
            int byt = r * 640 + (256 + e) * 2;
            *(__hip_bfloat16*)(L + (byt ^ ((r & 7) << 4))) = __float2bfloat16(v);
        }
    }
    __syncthreads();

    // ---- color layer 1: [g|de|sigma|0] (K=320) -> 128 cols relu, into cols 0..127
    gemm_layer<1, 10>(L, 0, ws + OFF_WC1, b_c1, wid * 16, lane);
    __syncthreads();

    // ---- color layer 2 + sigmoid -> rgb
    {
        int r = t >> 2, p = t & 3;
        float a0 = 0.f, a1 = 0.f, a2 = 0.f;
        int kb = p * 32;
        for (int kk = 0; kk < 4; ++kk) {
            int k = kb + kk * 8;
            int byt = r * 640 + k * 2;
            s8 v = *(const s8*)(L + (byt ^ ((r & 7) << 4)));
#pragma unroll
            for (int j = 0; j < 8; ++j) {
                float f = bf2f(v[j]);
                a0 += f * w_c2[0 * 128 + k + j];
                a1 += f * w_c2[1 * 128 + k + j];
                a2 += f * w_c2[2 * 128 + k + j];
            }
        }
        a0 += __shfl_xor(a0, 1); a0 += __shfl_xor(a0, 2);
        a1 += __shfl_xor(a1, 1); a1 += __shfl_xor(a1, 2);
        a2 += __shfl_xor(a2, 1); a2 += __shfl_xor(a2, 2);
        if (p == 0) {
            int o = (row0 + r) * 3;
            out[o + 0] = 1.f / (1.f + expf(-(a0 + b_c2[0])));
            out[o + 1] = 1.f / (1.f + expf(-(a1 + b_c2[1])));
            out[o + 2] = 1.f / (1.f + expf(-(a2 + b_c2[2])));
        }
    }
}

extern "C" void kernel_launch(void* const* d_in, const int* in_sizes, int n_in,
                              void* d_out, int out_size, void* d_ws, size_t ws_size,
                              hipStream_t stream) {
    const float* position = (const float*)d_in[0];
    const float* direction = (const float*)d_in[1];
    const float* w1_in = (const float*)d_in[2];
    const float* b1_in = (const float*)d_in[3];
    const float* w1_h  = (const float*)d_in[4];
    const float* b1_h  = (const float*)d_in[5];
    const float* w2_in = (const float*)d_in[6];
    const float* b2_in = (const float*)d_in[7];
    const float* w2_h  = (const float*)d_in[8];
    const float* b2_h  = (const float*)d_in[9];
    const float* w_sigma = (const float*)d_in[10];
    const float* b_sigma = (const float*)d_in[11];
    const float* w_c1  = (const float*)d_in[12];
    const float* b_c1  = (const float*)d_in[13];
    const float* w_c2  = (const float*)d_in[14];
    const float* b_c2  = (const float*)d_in[15];
    float* out = (float*)d_out;
    __hip_bfloat16* ws = (__hip_bfloat16*)d_ws;

    prep_weights<<<(WS_ELEMS + 255) / 256, 256, 0, stream>>>(
        w1_in, w1_h, w2_in, w2_h, w_c1, ws);

    nerf_fused<<<N_PTS / 128, 512, 0, stream>>>(
        position, direction, ws,
        b1_in, b1_h, b2_in, b2_h,
        w_sigma, b_sigma, b_c1, w_c2, b_c2, out);
}

// Round 3
// 295.654 us; speedup vs baseline: 3.8940x; 3.8940x over previous
//
#include <hip/hip_runtime.h>
#include <hip/hip_bf16.h>

#define N_PTS 262144
#define STEP_LEN 0.0016914558667664818f

using f32x4 = __attribute__((ext_vector_type(4))) float;
using s8 = __attribute__((ext_vector_type(8))) short;

__device__ __forceinline__ float bf2f(short s) {
    union { unsigned int u; float f; } v;
    v.u = ((unsigned int)(unsigned short)s) << 16;
    return v.f;
}
__device__ __forceinline__ short f2bf(float f) {
    __hip_bfloat16 h = __float2bfloat16(f);
    return *reinterpret_cast<short*>(&h);
}

// ---- workspace offsets (bf16 elements) ----
// Trunk layers: fragment-order [ks][nt][lane][8]:
//   n = nt*16 + (lane&15), A-phys k-slot = ks*32 + (lane>>4)*8 + j
// WC1: old B-style [ntile][ks][lane][8].
#define OFF_W1    0         // 2 ks   -> 16384
#define OFF_L1H0  16384     // 8 ks   -> 65536
#define OFF_L1H1  81920
#define OFF_L1H2  147456
#define OFF_W2    212992    // 10 ks  -> 81920
#define OFF_L2H0  294912
#define OFF_L2H1  360448
#define OFF_L2H2  425984
#define OFF_WC1   491520    // 8 nt x 10 ks -> 40960
#define WS_ELEMS  532480

// hidden-layer pack: slot (ks,hi,j) must hold W[n][f_B] with
// f_B = ks*32 + (j>>2)*16 + hi*4 + (j&3)   (the acc->B-frag permutation)
__device__ __forceinline__ float hid_val(const float* __restrict__ W, int e) {
    int j = e & 7, lane = (e >> 3) & 63, nt = (e >> 9) & 15, ks = e >> 13;
    int n = nt * 16 + (lane & 15), hi = lane >> 4;
    int f = ks * 32 + ((j >> 2) << 4) + hi * 4 + (j & 3);
    return W[n * 256 + f];
}

__global__ void prep_weights(const float* __restrict__ w1_in,
                             const float* __restrict__ w1_h,
                             const float* __restrict__ w2_in,
                             const float* __restrict__ w2_h,
                             const float* __restrict__ w_c1,
                             __hip_bfloat16* __restrict__ ws) {
    int i = blockIdx.x * blockDim.x + threadIdx.x;
    if (i >= WS_ELEMS) return;
    float v;
    if (i < OFF_L1H0) {              // L1in: pe input, identity k-map
        int e = i;
        int j = e & 7, lane = (e >> 3) & 63, nt = (e >> 9) & 15, ks = e >> 13;
        int n = nt * 16 + (lane & 15), hi = lane >> 4;
        int f = ks * 32 + hi * 8 + j;
        v = (f < 63) ? w1_in[n * 63 + f] : 0.f;
    } else if (i < OFF_W2) {         // 3x L1 hidden, permuted k-map
        int e = i - OFF_L1H0; int sub = e >> 16; e &= 65535;
        v = hid_val(w1_h + sub * 65536, e);
    } else if (i < OFF_L2H0) {       // L2in: h part permuted, pe part identity
        int e = i - OFF_W2;
        int j = e & 7, lane = (e >> 3) & 63, nt = (e >> 9) & 15, ks = e >> 13;
        int n = nt * 16 + (lane & 15), hi = lane >> 4;
        if (ks < 8) {
            int f = ks * 32 + ((j >> 2) << 4) + hi * 4 + (j & 3);
            v = w2_in[n * 319 + f];
        } else {
            int pf = (ks - 8) * 32 + hi * 8 + j;
            v = (pf < 63) ? w2_in[n * 319 + 256 + pf] : 0.f;
        }
    } else if (i < OFF_WC1) {        // 3x L2 hidden, permuted k-map
        int e = i - OFF_L2H0; int sub = e >> 16; e &= 65535;
        v = hid_val(w2_h + sub * 65536, e);
    } else {                         // WC1: old B-style, real feature order
        int e = i - OFF_WC1;
        int j = e & 7, lane = (e >> 3) & 63;
        int rest = e >> 9; int ks = rest % 10; int nt = rest / 10;
        int n = nt * 16 + (lane & 15), hi = lane >> 4;
        int k = ks * 32 + hi * 8 + j;
        v = (k < 283) ? w_c1[n * 283 + k] : 0.f;
    }
    ws[i] = __float2bfloat16(v);
}

__device__ __forceinline__ float enc3(int f, float x0, float x1, float x2) {
    if (f < 3) return (f == 0) ? x0 : ((f == 1) ? x1 : x2);
    if (f < 33) {
        int q = f - 3; int c = q / 10, o = q % 10;
        float xc = (c == 0) ? x0 : ((c == 1) ? x1 : x2);
        return __sinf(xc * (float)(1 << o));
    }
    if (f < 63) {
        int q = f - 33; int c = q / 10, o = q % 10;
        float xc = (c == 0) ? x0 : ((c == 1) ? x1 : x2);
        return __cosf(xc * (float)(1 << o));
    }
    return 0.f;
}

// color layer 1 (round-2-proven style): A from sCat, B from global packed WC1
__device__ __forceinline__ void gemm_color1(
    char* __restrict__ lds, const __hip_bfloat16* __restrict__ Wp,
    const float* __restrict__ bias, int m0, int n0, int lane) {
    const int rlo = lane & 15;
    const int asw = (rlo & 7) << 4;
    f32x4 acc[8][2];
#pragma unroll
    for (int mt = 0; mt < 8; ++mt) { acc[mt][0] = f32x4{0,0,0,0}; acc[mt][1] = f32x4{0,0,0,0}; }
    const s8* bptr0 = (const s8*)Wp + (n0 >> 4) * 640 + lane;
    const s8* bptr1 = bptr0 + 640;
    int abase[8];
#pragma unroll
    for (int mt = 0; mt < 8; ++mt) {
        int row = m0 + mt * 16 + rlo;
        abase[mt] = row * 640 + ((lane >> 4) << 4);
    }
#pragma unroll
    for (int ks = 0; ks < 10; ++ks) {
        s8 b0 = bptr0[ks * 64], b1 = bptr1[ks * 64];
#pragma unroll
        for (int mt = 0; mt < 8; ++mt) {
            s8 a = *(const s8*)(lds + ((abase[mt] + ks * 64) ^ asw));
            acc[mt][0] = __builtin_amdgcn_mfma_f32_16x16x32_bf16(a, b0, acc[mt][0], 0, 0, 0);
            acc[mt][1] = __builtin_amdgcn_mfma_f32_16x16x32_bf16(a, b1, acc[mt][1], 0, 0, 0);
        }
    }
    __syncthreads();
    const int rhi = (lane >> 4) << 2;
#pragma unroll
    for (int ntI = 0; ntI < 2; ++ntI) {
        int n = n0 + ntI * 16 + rlo;
        float bv = bias[n];
#pragma unroll
        for (int mt = 0; mt < 8; ++mt) {
#pragma unroll
            for (int r = 0; r < 4; ++r) {
                int row = m0 + mt * 16 + rhi + r;
                float x = fmaxf(acc[mt][ntI][r] + bv, 0.f);
                int byt = row * 640 + n * 2;
                *(__hip_bfloat16*)(lds + (byt ^ ((row & 7) << 4))) = __float2bfloat16(x);
            }
        }
    }
}

#define MFMA16 __builtin_amdgcn_mfma_f32_16x16x32_bf16

#define CHUNK1(WB, KSL, FA, FB) do { \
    _Pragma("unroll") \
    for (int nt = 0; nt < 16; ++nt) { \
        const s8 w = *(const s8*)((WB) + (((KSL)*16 + nt)*64 + lane)*16); \
        acc[nt][0] = MFMA16(w, (FA), acc[nt][0], 0, 0, 0); \
        acc[nt][1] = MFMA16(w, (FB), acc[nt][1], 0, 0, 0); \
    } } while (0)

#define CHUNK4(WB, KB) do { \
    _Pragma("unroll") \
    for (int ksl = 0; ksl < 4; ++ksl) { \
        _Pragma("unroll") \
        for (int nt = 0; nt < 16; ++nt) { \
            const s8 w = *(const s8*)((WB) + ((ksl*16 + nt)*64 + lane)*16); \
            acc[nt][0] = MFMA16(w, actA[(KB) + ksl], acc[nt][0], 0, 0, 0); \
            acc[nt][1] = MFMA16(w, actB[(KB) + ksl], acc[nt][1], 0, 0, 0); \
        } } } while (0)

#define CONVERT(BP) do { \
    _Pragma("unroll") \
    for (int nt = 0; nt < 16; ++nt) { \
        const f32x4 b4 = *(const f32x4*)((BP) + nt*16 + hi4); \
        _Pragma("unroll") \
        for (int r = 0; r < 4; ++r) { \
            actA[nt >> 1][((nt & 1) << 2) | r] = f2bf(fmaxf(acc[nt][0][r] + b4[r], 0.f)); \
            actB[nt >> 1][((nt & 1) << 2) | r] = f2bf(fmaxf(acc[nt][1][r] + b4[r], 0.f)); \
            acc[nt][0][r] = 0.f; acc[nt][1][r] = 0.f; \
        } } } while (0)

__global__ __launch_bounds__(512, 2) void nerf_fused(
    const float* __restrict__ pos, const float* __restrict__ dir,
    const __hip_bfloat16* __restrict__ ws,
    const float* __restrict__ b1_in, const float* __restrict__ b1_h,
    const float* __restrict__ b2_in, const float* __restrict__ b2_h,
    const float* __restrict__ w_sigma, const float* __restrict__ b_sigma,
    const float* __restrict__ b_c1,
    const float* __restrict__ w_c2, const float* __restrict__ b_c2,
    float* __restrict__ out) {

    __shared__ __align__(16) char Lds[163840];  // union: {B0,B1 wt dbuf} then sCat[256][320]
    char* const B0 = Lds;
    char* const B1 = Lds + 65536;

    const int t = threadIdx.x;
    const int lane = t & 63;
    const int wid = t >> 6;
    const int hi = lane >> 4;
    const int col = lane & 15;
    const int hi4 = hi * 4;
    const int row0 = blockIdx.x * 256;
    const char* wsB = (const char*)ws;

    auto stageC = [&](long srcEl, char* dst, int bytes) {
        const char* src = wsB + srcEl * 2;
        for (int rnd = 0; rnd < bytes; rnd += 8192) {
            int off = rnd + wid * 1024;
            __builtin_amdgcn_global_load_lds(
                (const unsigned int*)(src + off + lane * 16),
                (unsigned int*)(dst + off), 16, 0, 0);
        }
    };

    // ---- stage first chunk, compute pe into B-frags meanwhile ----
    stageC(OFF_W1, B0, 32768);

    s8 peA0, peA1, peB0, peB1;
    {
        int gA = row0 + wid * 32 + col;
        int gB = gA + 16;
        float xa0 = pos[gA*3], xa1 = pos[gA*3+1], xa2 = pos[gA*3+2];
        float xb0 = pos[gB*3], xb1 = pos[gB*3+1], xb2 = pos[gB*3+2];
#pragma unroll
        for (int j = 0; j < 8; ++j) {
            int f0 = hi * 8 + j, f1 = 32 + hi * 8 + j;
            peA0[j] = f2bf(enc3(f0, xa0, xa1, xa2));
            peA1[j] = f2bf(enc3(f1, xa0, xa1, xa2));
            peB0[j] = f2bf(enc3(f0, xb0, xb1, xb2));
            peB1[j] = f2bf(enc3(f1, xb0, xb1, xb2));
        }
    }

    f32x4 acc[16][2];
#pragma unroll
    for (int nt = 0; nt < 16; ++nt) { acc[nt][0] = f32x4{0,0,0,0}; acc[nt][1] = f32x4{0,0,0,0}; }
    s8 actA[8], actB[8];

    __syncthreads();                                    // c0 ready
    // ---- trunk pipeline: stage c(k) || compute c(k-1) ----
    stageC(OFF_L1H0, B1, 65536);
    CHUNK1(B0, 0, peA0, peB0); CHUNK1(B0, 1, peA1, peB1); CONVERT(b1_in);
    __syncthreads();
    stageC(OFF_L1H0 + 32768, B0, 65536);
    CHUNK4(B1, 0);
    __syncthreads();
    stageC(OFF_L1H1, B1, 65536);
    CHUNK4(B0, 4); CONVERT(b1_h + 0);
    __syncthreads();
    stageC(OFF_L1H1 + 32768, B0, 65536);
    CHUNK4(B1, 0);
    __syncthreads();
    stageC(OFF_L1H2, B1, 65536);
    CHUNK4(B0, 4); CONVERT(b1_h + 256);
    __syncthreads();
    stageC(OFF_L1H2 + 32768, B0, 65536);
    CHUNK4(B1, 0);
    __syncthreads();
    stageC(OFF_W2, B1, 65536);
    CHUNK4(B0, 4); CONVERT(b1_h + 512);
    __syncthreads();
    stageC(OFF_W2 + 32768, B0, 65536);
    CHUNK4(B1, 0);                                      // L2in ks0..3
    __syncthreads();
    stageC(OFF_W2 + 65536, B1, 32768);
    CHUNK4(B0, 4);                                      // L2in ks4..7
    __syncthreads();
    stageC(OFF_L2H0, B0, 65536);
    CHUNK1(B1, 0, peA0, peB0); CHUNK1(B1, 1, peA1, peB1);  // L2in pe part
    CONVERT(b2_in);
    __syncthreads();
    stageC(OFF_L2H0 + 32768, B1, 65536);
    CHUNK4(B0, 0);
    __syncthreads();
    stageC(OFF_L2H1, B0, 65536);
    CHUNK4(B1, 4); CONVERT(b2_h + 0);
    __syncthreads();
    stageC(OFF_L2H1 + 32768, B1, 65536);
    CHUNK4(B0, 0);
    __syncthreads();
    stageC(OFF_L2H2, B0, 65536);
    CHUNK4(B1, 4); CONVERT(b2_h + 256);
    __syncthreads();
    stageC(OFF_L2H2 + 32768, B1, 65536);
    CHUNK4(B0, 0);
    __syncthreads();
    CHUNK4(B1, 4);                                      // last trunk chunk
    __syncthreads();                                    // all wbuf reads done

    // ---- write g = relu(acc + b2_h[2]) to sCat (rows=points, cols=real f) ----
    {
        const float* bp = b2_h + 512;
#pragma unroll
        for (int nt = 0; nt < 16; ++nt) {
            const f32x4 b4 = *(const f32x4*)(bp + nt * 16 + hi4);
#pragma unroll
            for (int pt = 0; pt < 2; ++pt) {
                int row = wid * 32 + pt * 16 + col;
                ushort4 pk;
                pk.x = (unsigned short)f2bf(fmaxf(acc[nt][pt][0] + b4[0], 0.f));
                pk.y = (unsigned short)f2bf(fmaxf(acc[nt][pt][1] + b4[1], 0.f));
                pk.z = (unsigned short)f2bf(fmaxf(acc[nt][pt][2] + b4[2], 0.f));
                pk.w = (unsigned short)f2bf(fmaxf(acc[nt][pt][3] + b4[3], 0.f));
                int byt = row * 640 + (nt * 16 + hi4) * 2;
                *(ushort4*)(Lds + (byt ^ ((row & 7) << 4))) = pk;
            }
        }
    }
    __syncthreads();

    // ---- sigma head: alpha out + sigma feature into col 282 ----
    {
        int r = t >> 1, p = t & 1;
        float a = 0.f;
#pragma unroll
        for (int kk = 0; kk < 16; ++kk) {
            int k = p * 128 + kk * 8;
            int byt = r * 640 + k * 2;
            s8 v = *(const s8*)(Lds + (byt ^ ((r & 7) << 4)));
#pragma unroll
            for (int j = 0; j < 8; ++j) a += bf2f(v[j]) * w_sigma[k + j];
        }
        a += __shfl_xor(a, 1);
        float sr = a + b_sigma[0];
        if (p == 0) {
            out[3 * N_PTS + row0 + r] = 1.f - expf(-fmaxf(sr, 0.f) * STEP_LEN);
            int byt = r * 640 + 282 * 2;
            *(__hip_bfloat16*)(Lds + (byt ^ ((r & 7) << 4))) = __float2bfloat16(sr);
        }
    }

    // ---- dir encoding -> cols 256..319 (26 dims + zero pad; col 282 = sigma) ----
    {
        int r = t >> 1, p = t & 1;
        int g = row0 + r;
        float u0 = (dir[g*3+0] + 1.f) * 0.5f;
        float u1 = (dir[g*3+1] + 1.f) * 0.5f;
        float u2 = (dir[g*3+2] + 1.f) * 0.5f;
        for (int e = p; e < 64; e += 2) {
            if (e == 26) continue;
            float v = 0.f;
            if (e < 13) {
                int c = e / 5, o = e % 5;
                float uc = (c == 0) ? u0 : ((c == 1) ? u1 : u2);
                v = __sinf(uc * (float)(1 << o));
            } else if (e < 26) {
                int q = e - 13; int c = q / 5, o = q % 5;
                float uc = (c == 0) ? u0 : ((c == 1) ? u1 : u2);
                v = __cosf(uc * (float)(1 << o));
            }
            int byt = r * 640 + (256 + e) * 2;
            *(__hip_bfloat16*)(Lds + (byt ^ ((r & 7) << 4))) = __float2bfloat16(v);
        }
    }
    __syncthreads();

    // ---- color layer 1: K=320 -> 128 cols relu (in-place cols 0..127) ----
    gemm_color1(Lds, ws + OFF_WC1, b_c1, (wid >> 2) * 128, (wid & 3) * 32, lane);
    __syncthreads();

    // ---- color layer 2 + sigmoid -> rgb ----
    {
        int r = t >> 1, p = t & 1;
        float a0 = 0.f, a1 = 0.f, a2 = 0.f;
#pragma unroll
        for (int kk = 0; kk < 8; ++kk) {
            int k = p * 64 + kk * 8;
            int byt = r * 640 + k * 2;
            s8 v = *(const s8*)(Lds + (byt ^ ((r & 7) << 4)));
#pragma unroll
            for (int j = 0; j < 8; ++j) {
                float f = bf2f(v[j]);
                a0 += f * w_c2[0 * 128 + k + j];
                a1 += f * w_c2[1 * 128 + k + j];
                a2 += f * w_c2[2 * 128 + k + j];
            }
        }
        a0 += __shfl_xor(a0, 1);
        a1 += __shfl_xor(a1, 1);
        a2 += __shfl_xor(a2, 1);
        if (p == 0) {
            int o = (row0 + r) * 3;
            out[o + 0] = 1.f / (1.f + expf(-(a0 + b_c2[0])));
            out[o + 1] = 1.f / (1.f + expf(-(a1 + b_c2[1])));
            out[o + 2] = 1.f / (1.f + expf(-(a2 + b_c2[2])));
        }
    }
}

extern "C" void kernel_launch(void* const* d_in, const int* in_sizes, int n_in,
                              void* d_out, int out_size, void* d_ws, size_t ws_size,
                              hipStream_t stream) {
    const float* position = (const float*)d_in[0];
    const float* direction = (const float*)d_in[1];
    const float* w1_in = (const float*)d_in[2];
    const float* b1_in = (const float*)d_in[3];
    const float* w1_h  = (const float*)d_in[4];
    const float* b1_h  = (const float*)d_in[5];
    const float* w2_in = (const float*)d_in[6];
    const float* b2_in = (const float*)d_in[7];
    const float* w2_h  = (const float*)d_in[8];
    const float* b2_h  = (const float*)d_in[9];
    const float* w_sigma = (const float*)d_in[10];
    const float* b_sigma = (const float*)d_in[11];
    const float* w_c1  = (const float*)d_in[12];
    const float* b_c1  = (const float*)d_in[13];
    const float* w_c2  = (const float*)d_in[14];
    const float* b_c2  = (const float*)d_in[15];
    float* out = (float*)d_out;
    __hip_bfloat16* ws = (__hip_bfloat16*)d_ws;

    prep_weights<<<(WS_ELEMS + 255) / 256, 256, 0, stream>>>(
        w1_in, w1_h, w2_in, w2_h, w_c1, ws);

    nerf_fused<<<N_PTS / 256, 512, 0, stream>>>(
        position, direction, ws,
        b1_in, b1_h, b2_in, b2_h,
        w_sigma, b_sigma, b_c1, w_c2, b_c2, out);
}

// Round 4
// 269.533 us; speedup vs baseline: 4.2714x; 1.0969x over previous
//
#include <hip/hip_runtime.h>
#include <hip/hip_bf16.h>

#define N_PTS 262144
#define STEP_LEN 0.0016914558667664818f

using f32x4 = __attribute__((ext_vector_type(4))) float;
using s8 = __attribute__((ext_vector_type(8))) short;

__device__ __forceinline__ float bf2f(short s) {
    union { unsigned int u; float f; } v;
    v.u = ((unsigned int)(unsigned short)s) << 16;
    return v.f;
}
__device__ __forceinline__ short f2bf(float f) {
    __hip_bfloat16 h = __float2bfloat16(f);
    return *reinterpret_cast<short*>(&h);
}

// ---- workspace offsets (bf16 elements) ----
// Trunk: 30 contiguous 32KB chunks, fragment order [ks][nt16][lane][8]:
//   n = nt*16 + (lane&15);  k-slot = ks*32 + perm(hi,j)
// perm for hidden (acc->B-frag): f = ks*32 + (j>>2)*16 + hi*4 + (j&3)
// perm for pe-input chunks: f = ks*32 + hi*8 + j (identity)
#define OFF_W1    0         // 1 chunk  (2 ks, pe)
#define OFF_L1H0  16384     // chunks 1-4
#define OFF_L1H1  81920     // 5-8
#define OFF_L1H2  147456    // 9-12
#define OFF_W2    212992    // 13-17 (ks0-7 hidden-perm, ks8-9 pe)
#define OFF_L2H0  294912    // 18-21
#define OFF_L2H1  360448    // 22-25
#define OFF_L2H2  425984    // 26-29
#define OFF_C1G   491520    // [8ks][8nt][lane][8] = 32768 (chunks 30-31)
#define OFF_C1DE  524288    // [8nt][lane][8] = 4096 (chunk 32, 8KB)
#define OFF_WSIG  528384    // [8ks][4hi][8j] = 256
#define OFF_WC2   528640    // [3ch][4ks][4hi][8j] = 384
#define WS_ELEMS  529024

__device__ __forceinline__ float hid_val(const float* __restrict__ W, int e) {
    int j = e & 7, lane = (e >> 3) & 63, nt = (e >> 9) & 15, ks = e >> 13;
    int n = nt * 16 + (lane & 15), hi = lane >> 4;
    int f = ks * 32 + ((j >> 2) << 4) + hi * 4 + (j & 3);
    return W[n * 256 + f];
}

__global__ void prep_weights(const float* __restrict__ w1_in,
                             const float* __restrict__ w1_h,
                             const float* __restrict__ w2_in,
                             const float* __restrict__ w2_h,
                             const float* __restrict__ w_c1,
                             const float* __restrict__ w_sigma,
                             const float* __restrict__ w_c2,
                             __hip_bfloat16* __restrict__ ws) {
    int i = blockIdx.x * blockDim.x + threadIdx.x;
    if (i >= WS_ELEMS) return;
    float v;
    if (i < OFF_L1H0) {              // W1: pe input, identity k-map
        int e = i;
        int j = e & 7, lane = (e >> 3) & 63, nt = (e >> 9) & 15, ks = e >> 13;
        int n = nt * 16 + (lane & 15), hi = lane >> 4;
        int f = ks * 32 + hi * 8 + j;
        v = (f < 63) ? w1_in[n * 63 + f] : 0.f;
    } else if (i < OFF_W2) {         // 3x L1 hidden, permuted k-map
        int e = i - OFF_L1H0; int sub = e >> 16; e &= 65535;
        v = hid_val(w1_h + sub * 65536, e);
    } else if (i < OFF_L2H0) {       // W2: h part permuted, pe part identity
        int e = i - OFF_W2;
        int j = e & 7, lane = (e >> 3) & 63, nt = (e >> 9) & 15, ks = e >> 13;
        int n = nt * 16 + (lane & 15), hi = lane >> 4;
        if (ks < 8) {
            int f = ks * 32 + ((j >> 2) << 4) + hi * 4 + (j & 3);
            v = w2_in[n * 319 + f];
        } else {
            int pf = (ks - 8) * 32 + hi * 8 + j;
            v = (pf < 63) ? w2_in[n * 319 + 256 + pf] : 0.f;
        }
    } else if (i < OFF_C1G) {        // 3x L2 hidden, permuted k-map
        int e = i - OFF_L2H0; int sub = e >> 16; e &= 65535;
        v = hid_val(w2_h + sub * 65536, e);
    } else if (i < OFF_C1DE) {       // color1 g-part, permuted, 8 nt
        int e = i - OFF_C1G;
        int j = e & 7, lane = (e >> 3) & 63, nt = (e >> 9) & 7, ks = e >> 12;
        int n = nt * 16 + (lane & 15), hi = lane >> 4;
        int f = ks * 32 + ((j >> 2) << 4) + hi * 4 + (j & 3);
        v = w_c1[n * 283 + f];
    } else if (i < OFF_WSIG) {       // color1 de-part, identity k-map
        int e = i - OFF_C1DE;
        int j = e & 7, lane = (e >> 3) & 63, nt = (e >> 9) & 7;
        int n = nt * 16 + (lane & 15), hi = lane >> 4;
        int k = 256 + hi * 8 + j;
        v = (k < 283) ? w_c1[n * 283 + k] : 0.f;
    } else if (i < OFF_WC2) {        // sigma weights, permuted
        int e = i - OFF_WSIG;
        int j = e & 7, hi = (e >> 3) & 3, ks = e >> 5;
        int f = ks * 32 + ((j >> 2) << 4) + hi * 4 + (j & 3);
        v = w_sigma[f];
    } else {                         // color2 weights, permuted
        int e = i - OFF_WC2;
        int j = e & 7, hi = (e >> 3) & 3, ks = (e >> 5) & 3, ch = e >> 7;
        int f = ks * 32 + ((j >> 2) << 4) + hi * 4 + (j & 3);
        v = w_c2[ch * 128 + f];
    }
    ws[i] = __float2bfloat16(v);
}

__device__ __forceinline__ float enc3(int f, float x0, float x1, float x2) {
    if (f < 3) return (f == 0) ? x0 : ((f == 1) ? x1 : x2);
    if (f < 33) {
        int q = f - 3; int c = q / 10, o = q % 10;
        float xc = (c == 0) ? x0 : ((c == 1) ? x1 : x2);
        return __sinf(xc * (float)(1 << o));
    }
    if (f < 63) {
        int q = f - 33; int c = q / 10, o = q % 10;
        float xc = (c == 0) ? x0 : ((c == 1) ? x1 : x2);
        return __cosf(xc * (float)(1 << o));
    }
    return 0.f;
}

#define MFMA16 __builtin_amdgcn_mfma_f32_16x16x32_bf16

#define CHUNK1(WB, KSL, FA, FB) do { \
    _Pragma("unroll") \
    for (int nt = 0; nt < 16; ++nt) { \
        const s8 w = *(const s8*)((WB) + (((KSL)*16 + nt)*64 + lane)*16); \
        acc[nt][0] = MFMA16(w, (FA), acc[nt][0], 0, 0, 0); \
        acc[nt][1] = MFMA16(w, (FB), acc[nt][1], 0, 0, 0); \
    } } while (0)

#define CHUNK2(WB, KB) do { \
    _Pragma("unroll") \
    for (int ksl = 0; ksl < 2; ++ksl) { \
        _Pragma("unroll") \
        for (int nt = 0; nt < 16; ++nt) { \
            const s8 w = *(const s8*)((WB) + ((ksl*16 + nt)*64 + lane)*16); \
            acc[nt][0] = MFMA16(w, actA[(KB) + ksl], acc[nt][0], 0, 0, 0); \
            acc[nt][1] = MFMA16(w, actB[(KB) + ksl], acc[nt][1], 0, 0, 0); \
        } } } while (0)

#define CHUNKC4(WB, KB) do { \
    _Pragma("unroll") \
    for (int ksl = 0; ksl < 4; ++ksl) { \
        _Pragma("unroll") \
        for (int nt = 0; nt < 8; ++nt) { \
            const s8 w = *(const s8*)((WB) + ((ksl*8 + nt)*64 + lane)*16); \
            acc[nt][0] = MFMA16(w, actA[(KB) + ksl], acc[nt][0], 0, 0, 0); \
            acc[nt][1] = MFMA16(w, actB[(KB) + ksl], acc[nt][1], 0, 0, 0); \
        } } } while (0)

#define CHUNKCDE(WB) do { \
    _Pragma("unroll") \
    for (int nt = 0; nt < 8; ++nt) { \
        const s8 w = *(const s8*)((WB) + (nt*64 + lane)*16); \
        acc[nt][0] = MFMA16(w, deA, acc[nt][0], 0, 0, 0); \
        acc[nt][1] = MFMA16(w, deB, acc[nt][1], 0, 0, 0); \
    } } while (0)

#define CONVERT(BP) do { \
    _Pragma("unroll") \
    for (int nt = 0; nt < 16; ++nt) { \
        const f32x4 b4 = *(const f32x4*)((BP) + nt*16 + hi4); \
        _Pragma("unroll") \
        for (int r = 0; r < 4; ++r) { \
            actA[nt >> 1][((nt & 1) << 2) | r] = f2bf(fmaxf(acc[nt][0][r] + b4[r], 0.f)); \
            actB[nt >> 1][((nt & 1) << 2) | r] = f2bf(fmaxf(acc[nt][1][r] + b4[r], 0.f)); \
            acc[nt][0][r] = 0.f; acc[nt][1][r] = 0.f; \
        } } } while (0)

__global__ __launch_bounds__(256, 2) void nerf_fused(
    const float* __restrict__ pos, const float* __restrict__ dir,
    const __hip_bfloat16* __restrict__ ws,
    const float* __restrict__ b1_in, const float* __restrict__ b1_h,
    const float* __restrict__ b2_in, const float* __restrict__ b2_h,
    const float* __restrict__ b_sigma, const float* __restrict__ b_c1,
    const float* __restrict__ b_c2,
    float* __restrict__ out) {

    __shared__ __align__(16) char Lds[65536];
    char* const B0 = Lds;
    char* const B1 = Lds + 32768;

    const int t = threadIdx.x;
    const int lane = t & 63;
    const int wid = t >> 6;
    const int hi = lane >> 4;
    const int col = lane & 15;
    const int hi4 = hi * 4;
    const int row0 = blockIdx.x * 128;
    const int gA = row0 + wid * 32 + col;
    const int gB = gA + 16;
    const char* wsB = (const char*)ws;

    auto stageC = [&](int srcEl, char* dst, int bytes) {
        const char* src = wsB + (long)srcEl * 2;
        for (int rnd = 0; rnd < bytes; rnd += 4096) {
            int off = rnd + wid * 1024;
            __builtin_amdgcn_global_load_lds(
                (const unsigned int*)(src + off + lane * 16),
                (unsigned int*)(dst + off), 16, 0, 0);
        }
    };

    // ---- stage chunk 0, compute pe frags meanwhile ----
    stageC(OFF_W1, B0, 32768);

    s8 peA0, peA1, peB0, peB1;
    {
        float xa0 = pos[gA*3], xa1 = pos[gA*3+1], xa2 = pos[gA*3+2];
        float xb0 = pos[gB*3], xb1 = pos[gB*3+1], xb2 = pos[gB*3+2];
#pragma unroll
        for (int j = 0; j < 8; ++j) {
            int f0 = hi * 8 + j, f1 = 32 + hi * 8 + j;
            peA0[j] = f2bf(enc3(f0, xa0, xa1, xa2));
            peA1[j] = f2bf(enc3(f1, xa0, xa1, xa2));
            peB0[j] = f2bf(enc3(f0, xb0, xb1, xb2));
            peB1[j] = f2bf(enc3(f1, xb0, xb1, xb2));
        }
    }

    f32x4 acc[16][2];
#pragma unroll
    for (int nt = 0; nt < 16; ++nt) { acc[nt][0] = f32x4{0,0,0,0}; acc[nt][1] = f32x4{0,0,0,0}; }
    s8 actA[8], actB[8];

    __syncthreads();                                            // c0 ready
    // ---- trunk: 30 uniform 32KB chunks, stage(k+1) || compute(k) ----
    stageC(1*16384, B1, 32768);
    CHUNK1(B0, 0, peA0, peB0); CHUNK1(B0, 1, peA1, peB1); CONVERT(b1_in);
    __syncthreads();
    stageC( 2*16384, B0, 32768); CHUNK2(B1, 0); __syncthreads();                          // k1  L1H0
    stageC( 3*16384, B1, 32768); CHUNK2(B0, 2); __syncthreads();
    stageC( 4*16384, B0, 32768); CHUNK2(B1, 4); __syncthreads();
    stageC( 5*16384, B1, 32768); CHUNK2(B0, 6); CONVERT(b1_h + 0);   __syncthreads();
    stageC( 6*16384, B0, 32768); CHUNK2(B1, 0); __syncthreads();                          // L1H1
    stageC( 7*16384, B1, 32768); CHUNK2(B0, 2); __syncthreads();
    stageC( 8*16384, B0, 32768); CHUNK2(B1, 4); __syncthreads();
    stageC( 9*16384, B1, 32768); CHUNK2(B0, 6); CONVERT(b1_h + 256); __syncthreads();
    stageC(10*16384, B0, 32768); CHUNK2(B1, 0); __syncthreads();                          // L1H2
    stageC(11*16384, B1, 32768); CHUNK2(B0, 2); __syncthreads();
    stageC(12*16384, B0, 32768); CHUNK2(B1, 4); __syncthreads();
    stageC(13*16384, B1, 32768); CHUNK2(B0, 6); CONVERT(b1_h + 512); __syncthreads();
    stageC(14*16384, B0, 32768); CHUNK2(B1, 0); __syncthreads();                          // W2 g-part
    stageC(15*16384, B1, 32768); CHUNK2(B0, 2); __syncthreads();
    stageC(16*16384, B0, 32768); CHUNK2(B1, 4); __syncthreads();
    stageC(17*16384, B1, 32768); CHUNK2(B0, 6); __syncthreads();
    stageC(18*16384, B0, 32768);                                                          // W2 pe-part
    CHUNK1(B1, 0, peA0, peB0); CHUNK1(B1, 1, peA1, peB1); CONVERT(b2_in);
    __syncthreads();
    stageC(19*16384, B1, 32768); CHUNK2(B0, 0); __syncthreads();                          // L2H0
    stageC(20*16384, B0, 32768); CHUNK2(B1, 2); __syncthreads();
    stageC(21*16384, B1, 32768); CHUNK2(B0, 4); __syncthreads();
    stageC(22*16384, B0, 32768); CHUNK2(B1, 6); CONVERT(b2_h + 0);   __syncthreads();
    stageC(23*16384, B1, 32768); CHUNK2(B0, 0); __syncthreads();                          // L2H1
    stageC(24*16384, B0, 32768); CHUNK2(B1, 2); __syncthreads();
    stageC(25*16384, B1, 32768); CHUNK2(B0, 4); __syncthreads();
    stageC(26*16384, B0, 32768); CHUNK2(B1, 6); CONVERT(b2_h + 256); __syncthreads();
    stageC(27*16384, B1, 32768); CHUNK2(B0, 0); __syncthreads();                          // L2H2
    stageC(28*16384, B0, 32768); CHUNK2(B1, 2); __syncthreads();
    stageC(29*16384, B1, 32768); CHUNK2(B0, 4); __syncthreads();
    stageC(OFF_C1G,  B0, 32768); CHUNK2(B1, 6); CONVERT(b2_h + 512); __syncthreads();
    // g now in actA/actB frags; acc zeroed.

    // ---- k30: stage C1G hi-half; sigma head + alpha + de frags; color1 ks0-3 ----
    stageC(OFF_C1G + 16384, B1, 32768);
    float srA, srB;
    {
        float sA = 0.f, sB = 0.f;
#pragma unroll
        for (int ks = 0; ks < 8; ++ks) {
            const s8 wv = *(const s8*)(wsB + (OFF_WSIG + ks * 32 + hi * 8) * 2);
#pragma unroll
            for (int j = 0; j < 8; ++j) {
                sA += bf2f(actA[ks][j]) * bf2f(wv[j]);
                sB += bf2f(actB[ks][j]) * bf2f(wv[j]);
            }
        }
        sA += __shfl_xor(sA, 16); sA += __shfl_xor(sA, 32);
        sB += __shfl_xor(sB, 16); sB += __shfl_xor(sB, 32);
        srA = sA + b_sigma[0]; srB = sB + b_sigma[0];
        if (hi == 0) {
            out[3 * N_PTS + gA] = 1.f - __expf(-fmaxf(srA, 0.f) * STEP_LEN);
            out[3 * N_PTS + gB] = 1.f - __expf(-fmaxf(srB, 0.f) * STEP_LEN);
        }
    }
    s8 deA, deB;
    {
        float uA0 = (dir[gA*3+0] + 1.f) * 0.5f;
        float uA1 = (dir[gA*3+1] + 1.f) * 0.5f;
        float uA2 = (dir[gA*3+2] + 1.f) * 0.5f;
        float uB0 = (dir[gB*3+0] + 1.f) * 0.5f;
        float uB1 = (dir[gB*3+1] + 1.f) * 0.5f;
        float uB2 = (dir[gB*3+2] + 1.f) * 0.5f;
#pragma unroll
        for (int j = 0; j < 8; ++j) {
            int d = hi * 8 + j;
            float vA, vB;
            if (d < 13) {
                int c = d / 5, o = d % 5; float s = (float)(1 << o);
                vA = __sinf(((c == 0) ? uA0 : (c == 1) ? uA1 : uA2) * s);
                vB = __sinf(((c == 0) ? uB0 : (c == 1) ? uB1 : uB2) * s);
            } else if (d < 26) {
                int q = d - 13; int c = q / 5, o = q % 5; float s = (float)(1 << o);
                vA = __cosf(((c == 0) ? uA0 : (c == 1) ? uA1 : uA2) * s);
                vB = __cosf(((c == 0) ? uB0 : (c == 1) ? uB1 : uB2) * s);
            } else if (d == 26) {
                vA = srA; vB = srB;
            } else {
                vA = 0.f; vB = 0.f;
            }
            deA[j] = f2bf(vA); deB[j] = f2bf(vB);
        }
    }
    CHUNKC4(B0, 0);
    __syncthreads();

    // ---- k31: stage de chunk; color1 ks4-7 ----
    stageC(OFF_C1DE, B0, 8192);
    CHUNKC4(B1, 4);
    __syncthreads();

    // ---- k32: color1 de-part; then color2 + sigmoid -> rgb ----
    CHUNKCDE(B0);
    s8 c1A[4], c1B[4];
#pragma unroll
    for (int nt = 0; nt < 8; ++nt) {
        const f32x4 b4 = *(const f32x4*)(b_c1 + nt * 16 + hi4);
#pragma unroll
        for (int r = 0; r < 4; ++r) {
            c1A[nt >> 1][((nt & 1) << 2) | r] = f2bf(fmaxf(acc[nt][0][r] + b4[r], 0.f));
            c1B[nt >> 1][((nt & 1) << 2) | r] = f2bf(fmaxf(acc[nt][1][r] + b4[r], 0.f));
        }
    }
#pragma unroll
    for (int ch = 0; ch < 3; ++ch) {
        float rA = 0.f, rB = 0.f;
#pragma unroll
        for (int ks = 0; ks < 4; ++ks) {
            const s8 wv = *(const s8*)(wsB + (OFF_WC2 + (ch * 4 + ks) * 32 + hi * 8) * 2);
#pragma unroll
            for (int j = 0; j < 8; ++j) {
                rA += bf2f(c1A[ks][j]) * bf2f(wv[j]);
                rB += bf2f(c1B[ks][j]) * bf2f(wv[j]);
            }
        }
        rA += __shfl_xor(rA, 16); rA += __shfl_xor(rA, 32);
        rB += __shfl_xor(rB, 16); rB += __shfl_xor(rB, 32);
        if (hi == 0) {
            out[gA * 3 + ch] = 1.f / (1.f + __expf(-(rA + b_c2[ch])));
            out[gB * 3 + ch] = 1.f / (1.f + __expf(-(rB + b_c2[ch])));
        }
    }
}

extern "C" void kernel_launch(void* const* d_in, const int* in_sizes, int n_in,
                              void* d_out, int out_size, void* d_ws, size_t ws_size,
                              hipStream_t stream) {
    const float* position = (const float*)d_in[0];
    const float* direction = (const float*)d_in[1];
    const float* w1_in = (const float*)d_in[2];
    const float* b1_in = (const float*)d_in[3];
    const float* w1_h  = (const float*)d_in[4];
    const float* b1_h  = (const float*)d_in[5];
    const float* w2_in = (const float*)d_in[6];
    const float* b2_in = (const float*)d_in[7];
    const float* w2_h  = (const float*)d_in[8];
    const float* b2_h  = (const float*)d_in[9];
    const float* w_sigma = (const float*)d_in[10];
    const float* b_sigma = (const float*)d_in[11];
    const float* w_c1  = (const float*)d_in[12];
    const float* b_c1  = (const float*)d_in[13];
    const float* w_c2  = (const float*)d_in[14];
    const float* b_c2  = (const float*)d_in[15];
    float* out = (float*)d_out;
    __hip_bfloat16* ws = (__hip_bfloat16*)d_ws;

    prep_weights<<<(WS_ELEMS + 255) / 256, 256, 0, stream>>>(
        w1_in, w1_h, w2_in, w2_h, w_c1, w_sigma, w_c2, ws);

    nerf_fused<<<N_PTS / 128, 256, 0, stream>>>(
        position, direction, ws,
        b1_in, b1_h, b2_in, b2_h,
        b_sigma, b_c1, b_c2, out);
}